// Round 5
// baseline (766.833 us; speedup 1.0000x reference)
//
#include <hip/hip_runtime.h>
#include <stdint.h>

typedef unsigned short u16;
typedef uint32_t u32;
typedef _Float16 f16x8 __attribute__((ext_vector_type(8)));
typedef u16 u16x8 __attribute__((ext_vector_type(8)));
typedef float f32x4 __attribute__((ext_vector_type(4)));

#define MFMA(a,b,c) __builtin_amdgcn_mfma_f32_16x16x32_f16((a),(b),(c),0,0,0)

constexpr int SN = 512;          // sequence N
constexpr int CC = 128;          // channels (CZ == CI)
constexpr int PP = SN * SN;      // positions
constexpr float LNEPS = 1e-5f;
constexpr float LO_SCALE = 2048.0f;     // 2^11: keeps residuals normal in fp16
constexpr float LO_INV   = 1.0f / 2048.0f;

// RNE bf16 quantization of an fp32 value (matches the np reference's input
// quantization — confirmed by round 4's first-validation pass).
__device__ __forceinline__ float bq(float f){
    u32 u = __builtin_bit_cast(u32, f);
    u += 0x7fffu + ((u >> 16) & 1u);
    return __builtin_bit_cast(float, u & 0xffff0000u);
}

// split fp32 -> (hi, lo) fp16 pair; x ~= hi + lo*2^-11, input precision ~2^-22
__device__ __forceinline__ void split2(float x, u16& h, u16& l){
    _Float16 a = (_Float16)x;
    _Float16 b = (_Float16)((x - (float)a) * LO_SCALE);
    h = __builtin_bit_cast(u16, a);
    l = __builtin_bit_cast(u16, b);
}
__device__ __forceinline__ u16 f2h(float f){
    _Float16 h = (_Float16)f;
    return __builtin_bit_cast(u16, h);
}
__device__ __forceinline__ f16x8 ld_frag(const u16* p){
    return __builtin_bit_cast(f16x8, *(const u16x8*)p);
}
__device__ __forceinline__ float sigm(float x){ return 1.0f / (1.0f + __expf(-x)); }

// Load 64 rows x 128 cols fp32 weights (row stride 128) -> bf16-quantized,
// split fp16 LDS, stride 136
__device__ __forceinline__ void load_w64s(const float* __restrict__ src,
                                          u16* dh, u16* dl, int tid){
    const int r = tid >> 2, q = tid & 3;
    const float4* s4 = (const float4*)(src + (size_t)r * CC + q * 32);
    u16* ph = dh + r * 136 + q * 32;
    u16* pl = dl + r * 136 + q * 32;
    #pragma unroll
    for (int j = 0; j < 8; ++j){
        float4 v = s4[j];
        split2(bq(v.x), ph[j*4+0], pl[j*4+0]);
        split2(bq(v.y), ph[j*4+1], pl[j*4+1]);
        split2(bq(v.z), ph[j*4+2], pl[j*4+2]);
        split2(bq(v.w), ph[j*4+3], pl[j*4+3]);
    }
}

// LayerNorm of 64 positions of act (bf16-quantized) -> split fp16 LDS [pos][c]
__device__ __forceinline__ void ln_split(const float* __restrict__ act, int p0,
        const float* __restrict__ lnw, const float* __restrict__ lnb,
        u16* sLh, u16* sLl, int tid){
    const int pos = tid >> 2, q = tid & 3;
    const float4* a4 = (const float4*)(act + (size_t)(p0 + pos) * CC + q * 32);
    float4 av[8];
    float s = 0.f, s2 = 0.f;
    #pragma unroll
    for (int j = 0; j < 8; ++j){
        av[j] = a4[j];
        av[j].x = bq(av[j].x); av[j].y = bq(av[j].y);
        av[j].z = bq(av[j].z); av[j].w = bq(av[j].w);
        s  += av[j].x + av[j].y + av[j].z + av[j].w;
        s2 += av[j].x*av[j].x + av[j].y*av[j].y + av[j].z*av[j].z + av[j].w*av[j].w;
    }
    s  += __shfl_xor(s, 1);  s  += __shfl_xor(s, 2);
    s2 += __shfl_xor(s2, 1); s2 += __shfl_xor(s2, 2);
    const float mean = s * (1.f / CC);
    const float rstd = rsqrtf(s2 * (1.f / CC) - mean * mean + LNEPS);
    const float4* w4 = (const float4*)(lnw + q * 32);
    const float4* b4 = (const float4*)(lnb + q * 32);
    u16* ph = sLh + pos * 136 + q * 32;
    u16* pl = sLl + pos * 136 + q * 32;
    #pragma unroll
    for (int j = 0; j < 8; ++j){
        float4 w = w4[j], b = b4[j];
        split2((av[j].x - mean) * rstd * bq(w.x) + bq(b.x), ph[j*4+0], pl[j*4+0]);
        split2((av[j].y - mean) * rstd * bq(w.y) + bq(b.y), ph[j*4+1], pl[j*4+1]);
        split2((av[j].z - mean) * rstd * bq(w.z) + bq(b.z), ph[j*4+2], pl[j*4+2]);
        split2((av[j].w - mean) * rstd * bq(w.w) + bq(b.w), ph[j*4+3], pl[j*4+3]);
    }
}

// 64x64 split-precision GEMM tile: res[t] (t<4 col-tiles) for this wave's 16 rows
__device__ __forceinline__ void gemm64s(const u16* sLh, const u16* sLl,
        const u16* sWh, const u16* sWl, int wave, int lq, int lr, f32x4* res){
    f32x4 ah[4], al[4];
    #pragma unroll
    for (int t = 0; t < 4; ++t){ ah[t] = f32x4{0,0,0,0}; al[t] = f32x4{0,0,0,0}; }
    #pragma unroll
    for (int kk = 0; kk < 4; ++kk){
        const int ao = (wave*16 + lr) * 136 + kk * 32 + lq * 8;
        const f16x8 a_h = ld_frag(sLh + ao);
        const f16x8 a_l = ld_frag(sLl + ao);
        #pragma unroll
        for (int t = 0; t < 4; ++t){
            const int bo = (t*16 + lr) * 136 + kk * 32 + lq * 8;
            const f16x8 b_h = ld_frag(sWh + bo);
            const f16x8 b_l = ld_frag(sWl + bo);
            ah[t] = MFMA(a_h, b_h, ah[t]);
            al[t] = MFMA(a_h, b_l, al[t]);
            al[t] = MFMA(a_l, b_h, al[t]);
        }
    }
    #pragma unroll
    for (int t = 0; t < 4; ++t) res[t] = ah[t] + al[t] * LO_INV;
}

// ---------------------------------------------------------------------------
// Kernel 1: LN + gate/proj (split-precision MFMA) -> lp/rp fp16, (c,i,k) layout.
// Pure function of d_in: reads only inputs, writes only d_ws (lp/rp).
// ---------------------------------------------------------------------------
__global__ __launch_bounds__(256) void k1_ln_proj(
        const float* __restrict__ act,  const float* __restrict__ mask,
        const float* __restrict__ lnw,  const float* __restrict__ lnb,
        const float* __restrict__ projw,const float* __restrict__ projb,
        const float* __restrict__ gatew,const float* __restrict__ gateb,
        u16* __restrict__ lp, u16* __restrict__ rp)
{
    __shared__ __align__(16) u16 sLh[64*136], sLl[64*136];
    __shared__ __align__(16) u16 sW[2*64*136];   // weight hi|lo; reused as fp16 stage tile
    u16* sWh = sW;
    u16* sWl = sW + 64*136;

    const int tid  = threadIdx.x;
    const int p0   = blockIdx.x * 64;
    const int irow = p0 >> 9;
    const int k0   = p0 & 511;

    ln_split(act, p0, lnw, lnb, sLh, sLl, tid);

    const int wave = tid >> 6, lane = tid & 63, lq = lane >> 4, lr = lane & 15;
    const float4 mv = *(const float4*)(mask + p0 + wave*16 + lq*4);
    const float mr[4] = {bq(mv.x), bq(mv.y), bq(mv.z), bq(mv.w)};

    #pragma unroll 1
    for (int gh = 0; gh < 4; ++gh){
        const int g = gh >> 1, h = gh & 1;
        const int cb = g * 128 + h * 64;

        __syncthreads();                            // sT reads done; publishes sL on gh=0
        load_w64s(gatew + (size_t)cb * CC, sWh, sWl, tid);
        __syncthreads();
        f32x4 gres[4]; gemm64s(sLh, sLl, sWh, sWl, wave, lq, lr, gres);
        __syncthreads();                            // gate-weight reads done
        load_w64s(projw + (size_t)cb * CC, sWh, sWl, tid);
        __syncthreads();
        f32x4 pres[4]; gemm64s(sLh, sLl, sWh, sWl, wave, lq, lr, pres);
        __syncthreads();                            // proj-weight reads done

        u16* sT = sW;                               // 64x72 fp16 [col][pos]
        #pragma unroll
        for (int t = 0; t < 4; ++t){
            const int col = t * 16 + lr;
            const float qb = bq(gateb[cb + col]);
            const float pb = bq(projb[cb + col]);
            #pragma unroll
            for (int r = 0; r < 4; ++r){
                const int pos = wave * 16 + lq * 4 + r;
                sT[col * 72 + pos] =
                    f2h(mr[r] * (pres[t][r] + pb) * sigm(gres[t][r] + qb));
            }
        }
        __syncthreads();

        {   // cooperative transposed write: dst[c][i][k] contiguous along k, fp16
            const int cl = tid >> 2, q = tid & 3;
            u16* dst = (g ? rp : lp)
                     + (size_t)(h*64 + cl) * PP + (size_t)irow * SN + k0 + q * 16;
            const u16* s = sT + cl * 72 + q * 16;
            ((uint4*)dst)[0] = ((const uint4*)s)[0];
            ((uint4*)dst)[1] = ((const uint4*)s)[1];
        }
    }
}

// ---------------------------------------------------------------------------
// Kernel 2: outT[c][i][j] = sum_k lp[c][i][k]*rp[c][j][k], fp16 MFMA, fp32 acc,
// fp32 output (128 batched BT-GEMMs; block = 128x128 tile of one channel).
// ---------------------------------------------------------------------------
__global__ __launch_bounds__(256) void k2_einsum(
        const u16* __restrict__ lp, const u16* __restrict__ rp,
        float* __restrict__ outT)
{
    __shared__ __align__(16) u16 sA[128*72], sB[128*72];
    const int tid = threadIdx.x;
    const int c   = blockIdx.z;
    const int i0  = blockIdx.y * 128;
    const int j0  = blockIdx.x * 128;
    const u16* Ab = lp + (size_t)c * PP + (size_t)i0 * SN;
    const u16* Bb = rp + (size_t)c * PP + (size_t)j0 * SN;
    const int wave = tid >> 6, lane = tid & 63, lq = lane >> 4, lr = lane & 15;
    const int wi = (wave & 1) * 64, wj = (wave >> 1) * 64;
    const int row = tid >> 1, half = tid & 1;

    f32x4 acc[4][4];
    #pragma unroll
    for (int m = 0; m < 4; ++m)
        #pragma unroll
        for (int n = 0; n < 4; ++n) acc[m][n] = f32x4{0,0,0,0};

    for (int k0 = 0; k0 < SN; k0 += 64){
        const uint4* ga = (const uint4*)(Ab + (size_t)row * SN + k0 + half * 32);
        const uint4* gb = (const uint4*)(Bb + (size_t)row * SN + k0 + half * 32);
        uint4 a0 = ga[0], a1 = ga[1], a2 = ga[2], a3 = ga[3];
        uint4 b0 = gb[0], b1 = gb[1], b2 = gb[2], b3 = gb[3];
        __syncthreads();                          // prev iter's frag reads done
        uint4* da = (uint4*)(sA + row * 72 + half * 32);
        uint4* db = (uint4*)(sB + row * 72 + half * 32);
        da[0] = a0; da[1] = a1; da[2] = a2; da[3] = a3;
        db[0] = b0; db[1] = b1; db[2] = b2; db[3] = b3;
        __syncthreads();
        #pragma unroll
        for (int kk = 0; kk < 64; kk += 32){
            f16x8 af[4], bf[4];
            #pragma unroll
            for (int m = 0; m < 4; ++m)
                af[m] = ld_frag(sA + (wi + m*16 + lr) * 72 + kk + lq * 8);
            #pragma unroll
            for (int n = 0; n < 4; ++n)
                bf[n] = ld_frag(sB + (wj + n*16 + lr) * 72 + kk + lq * 8);
            #pragma unroll
            for (int m = 0; m < 4; ++m)
                #pragma unroll
                for (int n = 0; n < 4; ++n)
                    acc[m][n] = MFMA(af[m], bf[n], acc[m][n]);
        }
    }
    float* ob = outT + (size_t)c * PP;
    #pragma unroll
    for (int m = 0; m < 4; ++m){
        const int ir = i0 + wi + m * 16 + lq * 4;
        #pragma unroll
        for (int n = 0; n < 4; ++n){
            const int jc = j0 + wj + n * 16 + lr;
            #pragma unroll
            for (int r = 0; r < 4; ++r)
                ob[(size_t)(ir + r) * SN + jc] = acc[m][n][r];
        }
    }
}

// ---------------------------------------------------------------------------
// Kernel 3: gate = sigmoid(LN(act)@glw.T+glb) recomputed; channel-LN of outT;
// final = (LN_c(outT) @ outpw.T + outpb) * gate -> d_out (write-only, once).
// ---------------------------------------------------------------------------
__global__ __launch_bounds__(256) void k3_out(
        const float* __restrict__ act,  const float* __restrict__ outT,
        const float* __restrict__ lnw,  const float* __restrict__ lnb,
        const float* __restrict__ glw,  const float* __restrict__ glb,
        const float* __restrict__ cnw,  const float* __restrict__ cnb,
        const float* __restrict__ outpw,const float* __restrict__ outpb,
        float* __restrict__ io)
{
    // regionA (36864 B): phase1 sL pair | phase2 sRaw | phase2 outp-weight pair
    // regionB (34816 B): phase1 gl-weight pair | phase2 sLn pair
    __shared__ __align__(16) char smem[36864 + 34816];
    __shared__ float sRed[64 * 8];
    __shared__ float sStat[64 * 2];
    char* regA = smem;
    char* regB = smem + 36864;

    const int tid  = threadIdx.x;
    const int p0   = blockIdx.x * 64;
    const int irow = p0 >> 9;
    const int j0   = p0 & 511;
    const int wave = tid >> 6, lane = tid & 63, lq = lane >> 4, lr = lane & 15;

    // ---- phase 1: recompute sigmoid gate (fp32-grade, bf16-quantized inputs)
    u16* sLh = (u16*)regA; u16* sLl = sLh + 64*136;
    u16* sGh = (u16*)regB; u16* sGl = sGh + 64*136;
    ln_split(act, p0, lnw, lnb, sLh, sLl, tid);
    f32x4 gate[8];
    #pragma unroll 1
    for (int ch = 0; ch < 2; ++ch){
        __syncthreads();                         // publishes sL (ch=0) / frees sG (ch=1)
        load_w64s(glw + (size_t)(ch * 64) * CC, sGh, sGl, tid);
        __syncthreads();
        f32x4 res[4]; gemm64s(sLh, sLl, sGh, sGl, wave, lq, lr, res);
        #pragma unroll
        for (int t = 0; t < 4; ++t){
            const float gb = bq(glb[ch*64 + t*16 + lr]);
            f32x4 gv;
            #pragma unroll
            for (int r = 0; r < 4; ++r) gv[r] = sigm(res[t][r] + gb);
            gate[ch*4 + t] = gv;
        }
    }
    __syncthreads();                             // all sL/sG reads done

    // ---- phase 2: channel-LN of outT + output projection
    float* sRaw = (float*)regA;                  // [c][jj] fp32, stride 72
    {
        const int cc = tid >> 1, hf = tid & 1;
        const float4* g4 = (const float4*)(outT + (size_t)cc * PP + (size_t)irow * SN + j0 + hf * 32);
        float4 v[8];
        #pragma unroll
        for (int j = 0; j < 8; ++j) v[j] = g4[j];
        float4* d = (float4*)(sRaw + cc * 72 + hf * 32);
        #pragma unroll
        for (int j = 0; j < 8; ++j) d[j] = v[j];
    }
    __syncthreads();

    const int jj = tid & 63, cq = tid >> 6;
    {
        float s = 0.f, s2 = 0.f;
        #pragma unroll
        for (int t = 0; t < 32; ++t){
            float x = sRaw[(cq*32 + t) * 72 + jj];
            s += x; s2 += x * x;
        }
        sRed[jj*8 + cq] = s; sRed[jj*8 + 4 + cq] = s2;
    }
    __syncthreads();
    if (tid < 64){
        float s  = sRed[tid*8+0] + sRed[tid*8+1] + sRed[tid*8+2] + sRed[tid*8+3];
        float s2 = sRed[tid*8+4] + sRed[tid*8+5] + sRed[tid*8+6] + sRed[tid*8+7];
        float mean = s * (1.f / CC);
        sStat[tid*2+0] = mean;
        sStat[tid*2+1] = rsqrtf(s2 * (1.f / CC) - mean * mean + LNEPS);
    }
    __syncthreads();
    u16* sNh = (u16*)regB; u16* sNl = sNh + 64*136;   // sLn [jj][c] split
    {
        const float mean = sStat[jj*2+0], rstd = sStat[jj*2+1];
        #pragma unroll
        for (int t = 0; t < 32; ++t){
            const int ch = cq * 32 + t;
            const float x = (sRaw[ch * 72 + jj] - mean) * rstd * bq(cnw[ch]) + bq(cnb[ch]);
            split2(x, sNh[jj*136 + ch], sNl[jj*136 + ch]);
        }
    }
    u16* sOh = (u16*)regA; u16* sOl = sOh + 64*136;   // outp weights (overwrite sRaw)
    #pragma unroll 1
    for (int hf = 0; hf < 2; ++hf){
        __syncthreads();                         // sRaw reads done / prev weight reads done
        load_w64s(outpw + (size_t)(hf * 64) * CC, sOh, sOl, tid);
        __syncthreads();
        f32x4 res[4]; gemm64s(sNh, sNl, sOh, sOl, cq, lq, lr, res);
        #pragma unroll
        for (int t = 0; t < 4; ++t){
            const int col = hf*64 + t*16 + lr;
            const float ob = bq(outpb[col]);
            #pragma unroll
            for (int r = 0; r < 4; ++r){
                const int pos = p0 + cq*16 + lq*4 + r;
                io[(size_t)pos * CC + col] = (res[t][r] + ob) * gate[hf*4 + t][r];
            }
        }
    }
}

// ---------------------------------------------------------------------------
extern "C" void kernel_launch(void* const* d_in, const int* in_sizes, int n_in,
                              void* d_out, int out_size, void* d_ws, size_t ws_size,
                              hipStream_t stream)
{
    const float* act   = (const float*)d_in[0];
    const float* mask  = (const float*)d_in[1];
    const float* lnw   = (const float*)d_in[2];
    const float* lnb   = (const float*)d_in[3];
    const float* projw = (const float*)d_in[4];
    const float* projb = (const float*)d_in[5];
    const float* gatew = (const float*)d_in[6];
    const float* gateb = (const float*)d_in[7];
    const float* cnw   = (const float*)d_in[8];
    const float* cnb   = (const float*)d_in[9];
    const float* outpw = (const float*)d_in[10];
    const float* outpb = (const float*)d_in[11];
    const float* glw   = (const float*)d_in[12];
    const float* glb   = (const float*)d_in[13];

    // All scratch in d_ws; d_out is write-only (k3, once per element):
    //   lp fp16 (64MB) | rp fp16 (64MB) | outT fp32 (128MB) = 256MB
    u16*   lp   = (u16*)d_ws;
    u16*   rp   = lp + (size_t)PP * CC;
    float* outT = (float*)(rp + (size_t)PP * CC);

    k1_ln_proj<<<PP / 64, 256, 0, stream>>>(act, mask, lnw, lnb, projw, projb,
                                            gatew, gateb, lp, rp);
    k2_einsum<<<dim3(4, 4, 128), 256, 0, stream>>>(lp, rp, outT);
    k3_out<<<PP / 64, 256, 0, stream>>>(act, outT, lnw, lnb, glw, glb,
                                        cnw, cnb, outpw, outpb, (float*)d_out);
}